// Round 1
// baseline (195.454 us; speedup 1.0000x reference)
//
#include <hip/hip_runtime.h>
#include <hip/hip_bf16.h>

#define B_    2
#define S_    2048
#define DIN   1024
#define EMB   1024
#define NH    16
#define HD    64
#define N3    3072
#define MROWS 4096   // B_*S_

typedef short bf16x8 __attribute__((ext_vector_type(8)));
typedef float f32x4  __attribute__((ext_vector_type(4)));
typedef unsigned short u16;
typedef u16 u16x8 __attribute__((ext_vector_type(8)));
typedef u16 u16x4 __attribute__((ext_vector_type(4)));

__device__ __forceinline__ u16 f2bf(float f) {
  union { float f; unsigned u; } x; x.f = f;
  unsigned r = x.u + 0x7fffu + ((x.u >> 16) & 1u);
  return (u16)(r >> 16);
}

__device__ __forceinline__ void gload16(const void* g, void* l) {
  __builtin_amdgcn_global_load_lds(
      (const __attribute__((address_space(1))) unsigned int*)g,
      (__attribute__((address_space(3))) unsigned int*)l, 16, 0, 0);
}

__global__ void cast4(const float* __restrict__ in, u16* __restrict__ out, int n4) {
  const int i = blockIdx.x * 256 + threadIdx.x;
  if (i < n4) {
    const float4 v = ((const float4*)in)[i];
    u16x4 o;
    o[0] = f2bf(v.x); o[1] = f2bf(v.y); o[2] = f2bf(v.z); o[3] = f2bf(v.w);
    ((u16x4*)out)[i] = o;
  }
}

// C[m,n] = sum_k A[m,k] * W[n,k] + bias[n]; A:[M][K] bf16, W:[N][K] bf16 (both K-contiguous).
// EPI==0: scatter into Q/K/V [B,H,S,d] bf16 (Q scaled by 0.125). EPI==1: f32 out.
template<int EPI>
__global__ __launch_bounds__(256)
void gemm_bt(const u16* __restrict__ A, const u16* __restrict__ W,
             const float* __restrict__ bias, float* __restrict__ Cf,
             u16* __restrict__ Qb, u16* __restrict__ Kb, u16* __restrict__ Vb,
             int M, int N, int K) {
  __shared__ u16 Als[128 * 32];
  __shared__ u16 Bls[128 * 32];
  const int tid  = threadIdx.x;
  const int wave = tid >> 6, lane = tid & 63;
  const int lhi  = lane >> 4, llo = lane & 15;
  const int wr   = wave >> 1, wc = wave & 1;
  const int m0   = blockIdx.y * 128, n0 = blockIdx.x * 128;

  const f32x4 fzero = {0.f, 0.f, 0.f, 0.f};
  f32x4 acc[4][4];
#pragma unroll
  for (int m = 0; m < 4; ++m)
#pragma unroll
    for (int n = 0; n < 4; ++n) acc[m][n] = fzero;

  for (int k0 = 0; k0 < K; k0 += 32) {
#pragma unroll
    for (int i = 0; i < 2; ++i) {
      const int e   = (tid + i * 256) * 8;   // element index in [128][32] tile
      const int row = e >> 5, col = e & 31;
      gload16(A + (size_t)(m0 + row) * K + k0 + col, (char*)Als + wave * 1024 + i * 4096);
      gload16(W + (size_t)(n0 + row) * K + k0 + col, (char*)Bls + wave * 1024 + i * 4096);
    }
    __syncthreads();
    bf16x8 af[4], bfr[4];
#pragma unroll
    for (int m = 0; m < 4; ++m) af[m]  = *(const bf16x8*)&Als[(wr * 64 + m * 16 + llo) * 32 + lhi * 8];
#pragma unroll
    for (int n = 0; n < 4; ++n) bfr[n] = *(const bf16x8*)&Bls[(wc * 64 + n * 16 + llo) * 32 + lhi * 8];
#pragma unroll
    for (int m = 0; m < 4; ++m)
#pragma unroll
      for (int n = 0; n < 4; ++n)
        acc[m][n] = __builtin_amdgcn_mfma_f32_16x16x32_bf16(af[m], bfr[n], acc[m][n], 0, 0, 0);
    __syncthreads();
  }

#pragma unroll
  for (int n = 0; n < 4; ++n) {
    const int colb = n0 + wc * 64 + n * 16;  // 16-aligned block base; never crosses a 64-col section
    const int gcol = colb + llo;
    const float bv = bias[gcol];
    if (EPI == 0) {
      const int h   = colb / 192;
      const int rr  = colb - h * 192;
      const int sec = rr >> 6;               // 0:Q 1:K 2:V
      const int d   = (rr & 63) + llo;
      u16* dst = (sec == 0) ? Qb : (sec == 1) ? Kb : Vb;
      const float scl = (sec == 0) ? 0.125f : 1.0f;
#pragma unroll
      for (int m = 0; m < 4; ++m) {
        const int rowb = m0 + wr * 64 + m * 16 + lhi * 4;
#pragma unroll
        for (int r = 0; r < 4; ++r) {
          const int grow = rowb + r;         // b*S + s
          const int b = grow >> 11, s = grow & 2047;
          dst[(((size_t)(b * NH + h) * S_ + s) << 6) + d] = f2bf((acc[m][n][r] + bv) * scl);
        }
      }
    } else {
#pragma unroll
      for (int m = 0; m < 4; ++m) {
        const int rowb = m0 + wr * 64 + m * 16 + lhi * 4;
#pragma unroll
        for (int r = 0; r < 4; ++r)
          Cf[(size_t)(rowb + r) * N + gcol] = acc[m][n][r] + bv;
      }
    }
  }
}

// Flash attention fwd: grid (S/64, B*NH), 256 threads = 4 waves, 16 q-rows per wave.
// Q pre-scaled by 1/sqrt(d). Swapped QK^T: D[kv,q] = mfma(K, Q^T) so the softmax
// reduce over kv is 16 in-lane values + shfl_xor(16/32). Writes [B,S,H,d] bf16.
__global__ __launch_bounds__(256)
void attn_fwd(const u16* __restrict__ Qb, const u16* __restrict__ Kb,
              const u16* __restrict__ Vb, u16* __restrict__ Obf) {
  __shared__ u16 Kls[64 * 72];      // K tile [t][d], padded rows
  __shared__ u16 Vt [64 * 72];      // V^T tile [d][t]
  __shared__ u16 Pls[4][16 * 72];   // per-wave P [q][kv]
  const int tid  = threadIdx.x;
  const int wave = tid >> 6, lane = tid & 63;
  const int lhi  = lane >> 4, llo = lane & 15;
  const int bh   = blockIdx.y;
  const int q0   = blockIdx.x * 64;
  const size_t base = (size_t)bh * S_ * HD;

  bf16x8 qf[2];
#pragma unroll
  for (int kk = 0; kk < 2; ++kk)
    qf[kk] = *(const bf16x8*)&Qb[base + (size_t)(q0 + wave * 16 + llo) * HD + kk * 32 + lhi * 8];

  const f32x4 fzero = {0.f, 0.f, 0.f, 0.f};
  f32x4 o[4];
#pragma unroll
  for (int jd = 0; jd < 4; ++jd) o[jd] = fzero;
  float mrow = -1e30f, lsum = 0.f;

  const int r_ = tid >> 2, c0 = (tid & 3) * 16;  // staging assignment

  for (int t0 = 0; t0 < S_; t0 += 64) {
    // ---- stage K tile and transposed V tile ----
    {
      const u16x8* ks = (const u16x8*)&Kb[base + (size_t)(t0 + r_) * HD + c0];
      *(u16x8*)&Kls[r_ * 72 + c0]     = ks[0];
      *(u16x8*)&Kls[r_ * 72 + c0 + 8] = ks[1];
      const u16* vs = &Vb[base + (size_t)(t0 + r_) * HD + c0];
      u16x8 v0 = *(const u16x8*)vs;
      u16x8 v1 = *(const u16x8*)(vs + 8);
#pragma unroll
      for (int i = 0; i < 8; ++i) Vt[(c0 + i) * 72 + r_]     = v0[i];
#pragma unroll
      for (int i = 0; i < 8; ++i) Vt[(c0 + 8 + i) * 72 + r_] = v1[i];
    }
    __syncthreads();

    // ---- S = K @ Q^T : D[kv,q], 4 accs of 16 kv-rows ----
    f32x4 s[4];
#pragma unroll
    for (int j = 0; j < 4; ++j) s[j] = fzero;
#pragma unroll
    for (int j = 0; j < 4; ++j)
#pragma unroll
      for (int kk = 0; kk < 2; ++kk) {
        bf16x8 kf = *(const bf16x8*)&Kls[(j * 16 + llo) * 72 + kk * 32 + lhi * 8];
        s[j] = __builtin_amdgcn_mfma_f32_16x16x32_bf16(kf, qf[kk], s[j], 0, 0, 0);
      }

    // ---- online softmax (per q-col = llo; 4-lane group over lhi) ----
    float tmax = -1e30f;
#pragma unroll
    for (int j = 0; j < 4; ++j)
#pragma unroll
      for (int r = 0; r < 4; ++r) tmax = fmaxf(tmax, s[j][r]);
    tmax = fmaxf(tmax, __shfl_xor(tmax, 16));
    tmax = fmaxf(tmax, __shfl_xor(tmax, 32));
    const float mnew  = fmaxf(mrow, tmax);
    const float alpha = __expf(mrow - mnew);
    float tsum = 0.f;
#pragma unroll
    for (int j = 0; j < 4; ++j) {
      u16x4 pw;
#pragma unroll
      for (int r = 0; r < 4; ++r) {
        const float p = __expf(s[j][r] - mnew);
        tsum += p;
        pw[r] = f2bf(p);
      }
      *(u16x4*)&Pls[wave][llo * 72 + j * 16 + lhi * 4] = pw;
    }
    tsum += __shfl_xor(tsum, 16);
    tsum += __shfl_xor(tsum, 32);
    lsum = lsum * alpha + tsum;
    mrow = mnew;

    // ---- rescale O (factor indexed by q-row = lhi*4+r, held by lane lhi*4+r) ----
#pragma unroll
    for (int r = 0; r < 4; ++r) {
      const float f = __shfl(alpha, lhi * 4 + r);
#pragma unroll
      for (int jd = 0; jd < 4; ++jd) o[jd][r] *= f;
    }

    // ---- O += P @ V : D[q,d] ----
#pragma unroll
    for (int jd = 0; jd < 4; ++jd)
#pragma unroll
      for (int kk = 0; kk < 2; ++kk) {
        bf16x8 pf = *(const bf16x8*)&Pls[wave][llo * 72 + kk * 32 + lhi * 8];
        bf16x8 vf = *(const bf16x8*)&Vt[(jd * 16 + llo) * 72 + kk * 32 + lhi * 8];
        o[jd] = __builtin_amdgcn_mfma_f32_16x16x32_bf16(pf, vf, o[jd], 0, 0, 0);
      }
    __syncthreads();
  }

  // ---- finalize: /= lsum, write [B,S,H,d] bf16 ----
  const float li = 1.0f / lsum;
  const int b = bh >> 4, h = bh & 15;
#pragma unroll
  for (int r = 0; r < 4; ++r) {
    const float f = __shfl(li, lhi * 4 + r);
    const int q = q0 + wave * 16 + lhi * 4 + r;
    u16* dst = Obf + ((size_t)(b * S_ + q) * NH + h) * HD;
#pragma unroll
    for (int jd = 0; jd < 4; ++jd)
      dst[jd * 16 + llo] = f2bf(o[jd][r] * f);
  }
}

extern "C" void kernel_launch(void* const* d_in, const int* in_sizes, int n_in,
                              void* d_out, int out_size, void* d_ws, size_t ws_size,
                              hipStream_t stream) {
  const float* x     = (const float*)d_in[0];
  const float* qkv_w = (const float*)d_in[1];
  const float* qkv_b = (const float*)d_in[2];
  const float* o_w   = (const float*)d_in[3];
  const float* o_b   = (const float*)d_in[4];
  float* out = (float*)d_out;

  char* ws = (char*)d_ws;
  u16* xbf  = (u16*)(ws);                     // 8 MB; later aliased as attn output
  u16* wqkv = (u16*)(ws + (8u  << 20));       // 6 MB
  u16* wo   = (u16*)(ws + (14u << 20));       // 2 MB
  u16* Qb   = (u16*)(ws + (16u << 20));       // 8 MB  [B,H,S,d]
  u16* Kb   = (u16*)(ws + (24u << 20));       // 8 MB
  u16* Vb   = (u16*)(ws + (32u << 20));       // 8 MB
  u16* atnb = xbf;                            // [B,S,H,d] bf16 (x_bf is dead by then)

  cast4<<<4096, 256, 0, stream>>>(x,     xbf,  1048576);
  cast4<<<3072, 256, 0, stream>>>(qkv_w, wqkv,  786432);
  cast4<<<1024, 256, 0, stream>>>(o_w,   wo,    262144);

  gemm_bt<0><<<dim3(N3 / 128, MROWS / 128), 256, 0, stream>>>(
      xbf, wqkv, qkv_b, nullptr, Qb, Kb, Vb, MROWS, N3, DIN);

  attn_fwd<<<dim3(S_ / 64, B_ * NH), 256, 0, stream>>>(Qb, Kb, Vb, atnb);

  gemm_bt<1><<<dim3(EMB / 128, MROWS / 128), 256, 0, stream>>>(
      atnb, wo, o_b, out, nullptr, nullptr, nullptr, MROWS, EMB, EMB);
}

// Round 2
// 160.805 us; speedup vs baseline: 1.2155x; 1.2155x over previous
//
#include <hip/hip_runtime.h>
#include <hip/hip_bf16.h>

#define B_    2
#define S_    2048
#define DIN   1024
#define EMB   1024
#define NH    16
#define HD    64
#define N3    3072
#define MROWS 4096   // B_*S_
#define KVB   64
#define QBLK  128

typedef short bf16x8 __attribute__((ext_vector_type(8)));
typedef float f32x4  __attribute__((ext_vector_type(4)));
typedef unsigned short u16;
typedef u16 u16x8 __attribute__((ext_vector_type(8)));
typedef u16 u16x4 __attribute__((ext_vector_type(4)));
typedef unsigned int u32;

__device__ __forceinline__ u16 f2bf(float f) {
  union { float f; unsigned u; } x; x.f = f;
  unsigned r = x.u + 0x7fffu + ((x.u >> 16) & 1u);
  return (u16)(r >> 16);
}

__device__ __forceinline__ u32 cvtpk(float lo, float hi) {
  u32 r;
  asm("v_cvt_pk_bf16_f32 %0, %1, %2" : "=v"(r) : "v"(lo), "v"(hi));
  return r;
}

__device__ __forceinline__ void gload16(const void* g, void* l) {
  __builtin_amdgcn_global_load_lds(
      (const __attribute__((address_space(1))) unsigned int*)g,
      (__attribute__((address_space(3))) unsigned int*)l, 16, 0, 0);
}

__global__ void cast4(const float* __restrict__ in, u16* __restrict__ out, int n4) {
  const int i = blockIdx.x * 256 + threadIdx.x;
  if (i < n4) {
    const float4 v = ((const float4*)in)[i];
    u16x4 o;
    o[0] = f2bf(v.x); o[1] = f2bf(v.y); o[2] = f2bf(v.z); o[3] = f2bf(v.w);
    ((u16x4*)out)[i] = o;
  }
}

// C[m,n] = sum_k A[m,k] * W[n,k] + bias[n]; A:[M][K] bf16, W:[N][K] bf16.
// EPI==0: scatter Q,K -> [B,H,S,d] bf16 (Q scaled by 0.125*log2e), V -> V^T [B,H,d,S].
// EPI==1: f32 out.
template<int EPI>
__global__ __launch_bounds__(256)
void gemm_bt(const u16* __restrict__ A, const u16* __restrict__ W,
             const float* __restrict__ bias, float* __restrict__ Cf,
             u16* __restrict__ Qb, u16* __restrict__ Kb, u16* __restrict__ VbT,
             int M, int N, int K) {
  __shared__ u16 Als[128 * 32];
  __shared__ u16 Bls[128 * 32];
  const int tid  = threadIdx.x;
  const int wave = tid >> 6, lane = tid & 63;
  const int lhi  = lane >> 4, llo = lane & 15;
  const int wr   = wave >> 1, wc = wave & 1;
  const int m0   = blockIdx.y * 128, n0 = blockIdx.x * 128;

  const f32x4 fzero = {0.f, 0.f, 0.f, 0.f};
  f32x4 acc[4][4];
#pragma unroll
  for (int m = 0; m < 4; ++m)
#pragma unroll
    for (int n = 0; n < 4; ++n) acc[m][n] = fzero;

  for (int k0 = 0; k0 < K; k0 += 32) {
#pragma unroll
    for (int i = 0; i < 2; ++i) {
      const int e   = (tid + i * 256) * 8;   // element index in [128][32] tile
      const int row = e >> 5, col = e & 31;
      gload16(A + (size_t)(m0 + row) * K + k0 + col, (char*)Als + wave * 1024 + i * 4096);
      gload16(W + (size_t)(n0 + row) * K + k0 + col, (char*)Bls + wave * 1024 + i * 4096);
    }
    __syncthreads();
    bf16x8 af[4], bfr[4];
#pragma unroll
    for (int m = 0; m < 4; ++m) af[m]  = *(const bf16x8*)&Als[(wr * 64 + m * 16 + llo) * 32 + lhi * 8];
#pragma unroll
    for (int n = 0; n < 4; ++n) bfr[n] = *(const bf16x8*)&Bls[(wc * 64 + n * 16 + llo) * 32 + lhi * 8];
#pragma unroll
    for (int m = 0; m < 4; ++m)
#pragma unroll
      for (int n = 0; n < 4; ++n)
        acc[m][n] = __builtin_amdgcn_mfma_f32_16x16x32_bf16(af[m], bfr[n], acc[m][n], 0, 0, 0);
    __syncthreads();
  }

#pragma unroll
  for (int n = 0; n < 4; ++n) {
    const int colb = n0 + wc * 64 + n * 16;  // 16-aligned; never crosses a 64-col section
    const int gcol = colb + llo;
    const float bv = bias[gcol];
    if (EPI == 0) {
      const int h   = colb / 192;
      const int rr  = colb - h * 192;
      const int sec = rr >> 6;               // 0:Q 1:K 2:V
      const int d   = (rr & 63) + llo;
#pragma unroll
      for (int m = 0; m < 4; ++m) {
        const int rowb = m0 + wr * 64 + m * 16 + lhi * 4;
        const int b = rowb >> 11, s0 = rowb & 2047;
        if (sec == 2) {
          u16x4 vv;
#pragma unroll
          for (int r = 0; r < 4; ++r) vv[r] = f2bf(acc[m][n][r] + bv);
          *(u16x4*)&VbT[((size_t)(b * NH + h) * HD + d) * S_ + s0] = vv;
        } else {
          u16* dst = (sec == 0) ? Qb : Kb;
          const float scl = (sec == 0) ? 0.18033688f : 1.0f;  // 0.125*log2(e) for Q
#pragma unroll
          for (int r = 0; r < 4; ++r)
            dst[(((size_t)(b * NH + h) * S_ + s0 + r) << 6) + d] = f2bf((acc[m][n][r] + bv) * scl);
        }
      }
    } else {
#pragma unroll
      for (int m = 0; m < 4; ++m) {
        const int rowb = m0 + wr * 64 + m * 16 + lhi * 4;
#pragma unroll
        for (int r = 0; r < 4; ++r)
          Cf[(size_t)(rowb + r) * N + gcol] = acc[m][n][r] + bv;
      }
    }
  }
}

// Flash attention fwd: grid (S/QBLK, B*NH), 512 threads = 8 waves, 16 q-rows/wave.
// Q pre-scaled by log2(e)/sqrt(d); exp2-domain online softmax.
// K [B,H,S,d] and V^T [B,H,d,S] staged via global_load_lds with inverse-swizzled
// source; reads use byte = row*128 + ((slot ^ (row&7))<<4) (conflict-free).
// Swapped QK^T (D[kv,q]); P kept in registers via cvt_pk + shfl redistribution.
__global__ __launch_bounds__(512)
void attn_fwd(const u16* __restrict__ Qb, const u16* __restrict__ Kb,
              const u16* __restrict__ VbT, u16* __restrict__ Obf) {
  __shared__ __align__(16) u16 Kls[2][KVB * HD];
  __shared__ __align__(16) u16 Vls[2][HD * KVB];
  const int tid  = threadIdx.x;
  const int wave = tid >> 6, lane = tid & 63;
  const int lhi  = lane >> 4, llo = lane & 15;
  const int bh   = blockIdx.y;
  const int q0   = blockIdx.x * QBLK;
  const size_t base  = (size_t)bh * S_ * HD;   // Q, K
  const size_t basev = (size_t)bh * HD * S_;   // V^T

  // Q fragments: rows q0 + wave*16 + llo
  bf16x8 qf[2];
#pragma unroll
  for (int kk = 0; kk < 2; ++kk)
    qf[kk] = *(const bf16x8*)&Qb[base + (size_t)(q0 + wave * 16 + llo) * HD + kk * 32 + lhi * 8];

  // staging: 512 threads x 16B = one 8KB tile; LDS dest is linear (slot=tid),
  // global source is inverse-swizzled so swizzled reads return plain (row,slot)
  const int srow  = tid >> 3;                      // 0..63
  const int xslot = (tid & 7) ^ (srow & 7);
  const u16* kSrc = Kb  + base  + (size_t)srow * HD + xslot * 8;
  const u16* vSrc = VbT + basev + (size_t)srow * S_ + xslot * 8;
  const int ldsOff = wave * 1024;

  // swizzled read byte-offsets for row llo (+j*2048), slots kk*4+lhi
  const int ro  = llo * 128;
  const int sw0 = ((((0 * 4 + lhi) ^ (llo & 7)) << 4)) + ro;
  const int sw1 = ((((1 * 4 + lhi) ^ (llo & 7)) << 4)) + ro;

  const f32x4 fzero = {0.f, 0.f, 0.f, 0.f};
  f32x4 o[4];
#pragma unroll
  for (int jd = 0; jd < 4; ++jd) o[jd] = fzero;
  float mrow = -1e30f, lsum = 0.f;

  gload16(kSrc, (char*)Kls[0] + ldsOff);
  gload16(vSrc, (char*)Vls[0] + ldsOff);
  __syncthreads();

  int cur = 0;
  for (int t = 0; t < S_ / KVB; ++t) {
    if (t + 1 < S_ / KVB) {
      gload16(kSrc + (size_t)(t + 1) * KVB * HD, (char*)Kls[cur ^ 1] + ldsOff);
      gload16(vSrc + (t + 1) * KVB,              (char*)Vls[cur ^ 1] + ldsOff);
    }
    const char* Kt = (const char*)Kls[cur];
    const char* Vt = (const char*)Vls[cur];

    // ---- S = K @ Q^T : D[kv,q] ----
    f32x4 s[4];
#pragma unroll
    for (int j = 0; j < 4; ++j) s[j] = fzero;
    __builtin_amdgcn_s_setprio(1);
#pragma unroll
    for (int j = 0; j < 4; ++j) {
      bf16x8 k0 = *(const bf16x8*)(Kt + sw0 + j * 2048);
      bf16x8 k1 = *(const bf16x8*)(Kt + sw1 + j * 2048);
      s[j] = __builtin_amdgcn_mfma_f32_16x16x32_bf16(k0, qf[0], s[j], 0, 0, 0);
      s[j] = __builtin_amdgcn_mfma_f32_16x16x32_bf16(k1, qf[1], s[j], 0, 0, 0);
    }
    __builtin_amdgcn_s_setprio(0);

    // ---- online softmax (exp2 domain; stats per q-col = llo) ----
    float tmax = -1e30f;
#pragma unroll
    for (int j = 0; j < 4; ++j)
#pragma unroll
      for (int r = 0; r < 4; ++r) tmax = fmaxf(tmax, s[j][r]);
    tmax = fmaxf(tmax, __shfl_xor(tmax, 16));
    tmax = fmaxf(tmax, __shfl_xor(tmax, 32));
    const float mnew  = fmaxf(mrow, tmax);
    const float alpha = exp2f(mrow - mnew);
    float tsum = 0.f;
    u32 dwp[4][2];
#pragma unroll
    for (int j = 0; j < 4; ++j) {
      const float p0 = exp2f(s[j][0] - mnew), p1 = exp2f(s[j][1] - mnew);
      const float p2 = exp2f(s[j][2] - mnew), p3 = exp2f(s[j][3] - mnew);
      tsum += (p0 + p1) + (p2 + p3);
      dwp[j][0] = cvtpk(p0, p1);
      dwp[j][1] = cvtpk(p2, p3);
    }
    tsum += __shfl_xor(tsum, 16);
    tsum += __shfl_xor(tsum, 32);
    lsum = lsum * alpha + tsum;
    mrow = mnew;

    // ---- redistribute P -> A-fragment layout (in-register) ----
    // target dword m: dw[kk*2+(lhi>>1)][m&1] from lane llo+16*((lhi&1)*2+(m>>1))
    const int l0 = llo + ((lhi & 1) << 5);
    const int l1 = l0 + 16;
    const bool hi = (lhi & 2) != 0;
    bf16x8 pf[2];
#pragma unroll
    for (int kk = 0; kk < 2; ++kk) {
      const u32 a0 = __shfl(dwp[kk * 2][0], l0),     a1 = __shfl(dwp[kk * 2][1], l0);
      const u32 b0 = __shfl(dwp[kk * 2 + 1][0], l0), b1 = __shfl(dwp[kk * 2 + 1][1], l0);
      const u32 c0 = __shfl(dwp[kk * 2][0], l1),     c1 = __shfl(dwp[kk * 2][1], l1);
      const u32 d0 = __shfl(dwp[kk * 2 + 1][0], l1), d1 = __shfl(dwp[kk * 2 + 1][1], l1);
      union { u32 u[4]; bf16x8 v; } P;
      P.u[0] = hi ? b0 : a0;  P.u[1] = hi ? b1 : a1;
      P.u[2] = hi ? d0 : c0;  P.u[3] = hi ? d1 : c1;
      pf[kk] = P.v;
    }

    // ---- rescale O (factor for q-row lhi*4+r held by lane lhi*4+r) ----
#pragma unroll
    for (int r = 0; r < 4; ++r) {
      const float f = __shfl(alpha, lhi * 4 + r);
#pragma unroll
      for (int jd = 0; jd < 4; ++jd) o[jd][r] *= f;
    }

    // ---- O += P @ V : D[q,d] ----
    __builtin_amdgcn_s_setprio(1);
#pragma unroll
    for (int jd = 0; jd < 4; ++jd) {
      bf16x8 v0 = *(const bf16x8*)(Vt + sw0 + jd * 2048);
      bf16x8 v1 = *(const bf16x8*)(Vt + sw1 + jd * 2048);
      o[jd] = __builtin_amdgcn_mfma_f32_16x16x32_bf16(pf[0], v0, o[jd], 0, 0, 0);
      o[jd] = __builtin_amdgcn_mfma_f32_16x16x32_bf16(pf[1], v1, o[jd], 0, 0, 0);
    }
    __builtin_amdgcn_s_setprio(0);

    __syncthreads();   // drains vmcnt (next-tile gloads) + protects buffer swap
    cur ^= 1;
  }

  // ---- finalize: /= lsum, write [B,S,H,d] bf16 ----
  const float li = 1.0f / lsum;
  const int b = bh >> 4, h = bh & 15;
#pragma unroll
  for (int r = 0; r < 4; ++r) {
    const float f = __shfl(li, lhi * 4 + r);
    const int q = q0 + wave * 16 + lhi * 4 + r;
    u16* dst = Obf + ((size_t)(b * S_ + q) * NH + h) * HD;
#pragma unroll
    for (int jd = 0; jd < 4; ++jd)
      dst[jd * 16 + llo] = f2bf(o[jd][r] * f);
  }
}

extern "C" void kernel_launch(void* const* d_in, const int* in_sizes, int n_in,
                              void* d_out, int out_size, void* d_ws, size_t ws_size,
                              hipStream_t stream) {
  const float* x     = (const float*)d_in[0];
  const float* qkv_w = (const float*)d_in[1];
  const float* qkv_b = (const float*)d_in[2];
  const float* o_w   = (const float*)d_in[3];
  const float* o_b   = (const float*)d_in[4];
  float* out = (float*)d_out;

  char* ws = (char*)d_ws;
  u16* xbf  = (u16*)(ws);                     // 8 MB; later aliased as attn output
  u16* wqkv = (u16*)(ws + (8u  << 20));       // 6 MB
  u16* wo   = (u16*)(ws + (14u << 20));       // 2 MB
  u16* Qb   = (u16*)(ws + (16u << 20));       // 8 MB  [B,H,S,d]
  u16* Kb   = (u16*)(ws + (24u << 20));       // 8 MB  [B,H,S,d]
  u16* VbT  = (u16*)(ws + (32u << 20));       // 8 MB  [B,H,d,S]
  u16* atnb = xbf;                            // [B,S,H,d] bf16 (x_bf dead by then)

  cast4<<<4096, 256, 0, stream>>>(x,     xbf,  1048576);
  cast4<<<3072, 256, 0, stream>>>(qkv_w, wqkv,  786432);
  cast4<<<1024, 256, 0, stream>>>(o_w,   wo,    262144);

  gemm_bt<0><<<dim3(N3 / 128, MROWS / 128), 256, 0, stream>>>(
      xbf, wqkv, qkv_b, nullptr, Qb, Kb, VbT, MROWS, N3, DIN);

  attn_fwd<<<dim3(S_ / QBLK, B_ * NH), 512, 0, stream>>>(Qb, Kb, VbT, atnb);

  gemm_bt<1><<<dim3(EMB / 128, MROWS / 128), 256, 0, stream>>>(
      atnb, wo, o_b, out, nullptr, nullptr, nullptr, MROWS, EMB, EMB);
}